// Round 8
// baseline (181.500 us; speedup 1.0000x reference)
//
#include <hip/hip_runtime.h>
#include <hip/hip_bf16.h>
#include <stdint.h>

typedef __attribute__((ext_vector_type(8))) short  short8;   // 8 bf16 (4 VGPR) MFMA A/B frag
typedef __attribute__((ext_vector_type(4))) short  short4v;
typedef __attribute__((ext_vector_type(4))) float  float4v;  // MFMA C/D frag

#define MFMA16(a, b, c) __builtin_amdgcn_mfma_f32_16x16x32_bf16((a), (b), (c), 0, 0, 0)

#define S_LEN  4096
#define NBATCH 4
#define EMB    1024
#define DD     64
#define NROWS  (NBATCH * S_LEN)  // 16384
#define SCL2   0.1803368801111204f  // (1/sqrt(64)) * log2(e), folded into Wq at wcvt

#define AS1 const __attribute__((address_space(1))) unsigned int*
#define AS3 __attribute__((address_space(3))) unsigned int*

static __device__ __forceinline__ short f2bf(float f) {
  uint32_t u = __float_as_uint(f);
  return (short)((u + 0x7FFFu + ((u >> 16) & 1u)) >> 16);
}
static __device__ __forceinline__ unsigned pk2(float a, float b) {
  union { __hip_bfloat162 h; unsigned u; } z;
  z.h = __float22bfloat162_rn(make_float2(a, b));
  return z.u;
}
static __device__ __forceinline__ short8 cvt8(float4v a, float4v b) {
  union { unsigned u[4]; short8 s; } z;
  z.u[0] = pk2(a[0], a[1]); z.u[1] = pk2(a[2], a[3]);
  z.u[2] = pk2(b[0], b[1]); z.u[3] = pk2(b[2], b[3]);
  return z.s;
}

// ============ Kernel 0: W fp32 -> bf16, reordered into 32-k panels ============
__global__ void wcvt_kernel(const float* __restrict__ Wq, const float* __restrict__ Wk,
                            const float* __restrict__ Wv, short* __restrict__ Wb2) {
  const int t   = blockIdx.x * 256 + threadIdx.x;
  const int row = t >> 7;
  const int k   = (t & 127) * 8;
  const float* src = (row < 64) ? (Wq + (size_t)row * EMB)
                   : (row < 128) ? (Wk + (size_t)(row - 64) * EMB)
                                 : (Wv + (size_t)(row - 128) * EMB);
  const float sc = (row < 64) ? SCL2 : 1.0f;
  float4v a = *(const float4v*)(src + k);
  float4v b = *(const float4v*)(src + k + 4);
#pragma unroll
  for (int i = 0; i < 4; ++i) { a[i] *= sc; b[i] *= sc; }
  *(short8*)(Wb2 + (((k >> 5) * 192 + row) << 5) + (k & 31)) = cvt8(a, b);
}

// ======================= Kernel 1: QKV projection GEMM =======================
// (unchanged from round 6 -- DMA double-buffered, working)
__global__ __launch_bounds__(256, 2) void qkv_kernel(
    const float* __restrict__ x, const short* __restrict__ Wb2,
    short* __restrict__ Qb, short* __restrict__ Kb, short* __restrict__ Vt) {
  __shared__ float As[2][2048];
  __shared__ short Bs[2][12288];

  const int tid  = threadIdx.x;
  const int w    = tid >> 6;
  const int lane = tid & 63;
  const int ln   = lane & 15;
  const int quad = lane >> 4;
  const int m0   = blockIdx.x * 32;
  const int wr   = w & 1;
  const int wc   = w >> 1;

  const int tA0 = 2 * w, tA1 = 2 * w + 1;
  const float* xA0 = x + (size_t)(m0 + ((tA0 >> 2) << 4) + (lane >> 2)) * EMB
                       + ((tA0 & 3) * 4 + (lane & 3)) * 4;
  const float* xA1 = x + (size_t)(m0 + ((tA1 >> 2) << 4) + (lane >> 2)) * EMB
                       + ((tA1 & 3) * 4 + (lane & 3)) * 4;
  const short* wB = Wb2 + (size_t)(6 * w) * 512 + lane * 8;

#define STAGE(S, BUF) do {                                                      \
    __builtin_amdgcn_global_load_lds((AS1)(xA0 + (S) * 64),                     \
        (AS3)&As[BUF][tA0 * 256], 16, 0, 0);                                    \
    __builtin_amdgcn_global_load_lds((AS1)(xA1 + (S) * 64),                     \
        (AS3)&As[BUF][tA1 * 256], 16, 0, 0);                                    \
    _Pragma("unroll")                                                           \
    for (int j = 0; j < 6; ++j)                                                 \
      __builtin_amdgcn_global_load_lds((AS1)(wB + (size_t)(S) * 12288 + j * 512),\
          (AS3)&Bs[BUF][(6 * w + j) * 512], 16, 0, 0);                          \
  } while (0)

  const float4v zz = {0.f, 0.f, 0.f, 0.f};
  float4v acc[6] = {zz, zz, zz, zz, zz, zz};

  STAGE(0, 0);
  int buf = 0;
  for (int s = 0; s < 16; ++s) {
    __syncthreads();
    if (s + 1 < 16) STAGE(s + 1, buf ^ 1);
    short8 aF[2];
#pragma unroll
    for (int h = 0; h < 2; ++h) {
      const int ai = (wr * 4 + 2 * h + (quad >> 1)) * 256 + (ln * 4 + (quad & 1) * 2) * 4;
      const float4v lo = *(const float4v*)&As[buf][ai];
      const float4v hi = *(const float4v*)&As[buf][ai + 4];
      aF[h] = cvt8(lo, hi);
    }
#pragma unroll
    for (int f = 0; f < 6; ++f) {
      const int cf = wc * 6 + f;
      const short8 b0 = *(const short8*)&Bs[buf][(cf * 16 + ln) * 32 + quad * 8];
      const short8 b1 = *(const short8*)&Bs[buf][6144 + (cf * 16 + ln) * 32 + quad * 8];
      if (wc == 0 || f < 2) {
        acc[f] = MFMA16(aF[0], b0, acc[f]);
        acc[f] = MFMA16(aF[1], b1, acc[f]);
      } else {
        acc[f] = MFMA16(b0, aF[0], acc[f]);
        acc[f] = MFMA16(b1, aF[1], acc[f]);
      }
    }
    buf ^= 1;
  }
#undef STAGE

  const int b  = m0 >> 12;
  const int sb = m0 & (S_LEN - 1);
  if (wc == 0) {
#pragma unroll
    for (int f = 0; f < 6; ++f)
#pragma unroll
      for (int r = 0; r < 4; ++r) {
        const int row = m0 + wr * 16 + quad * 4 + r;
        if (f < 4) Qb[(size_t)row * DD + f * 16 + ln] = f2bf(acc[f][r]);
        else       Kb[(size_t)row * DD + (f - 4) * 16 + ln] = f2bf(acc[f][r]);
      }
  } else {
#pragma unroll
    for (int f = 0; f < 2; ++f)
#pragma unroll
      for (int r = 0; r < 4; ++r) {
        const int row = m0 + wr * 16 + quad * 4 + r;
        Kb[(size_t)row * DD + 32 + f * 16 + ln] = f2bf(acc[f][r]);
      }
#pragma unroll
    for (int f = 2; f < 6; ++f)
#pragma unroll
      for (int r = 0; r < 4; ++r) {
        const int d = (f - 2) * 16 + quad * 4 + r;
        Vt[((size_t)b * DD + d) * S_LEN + sb + wr * 16 + ln] = f2bf(acc[f][r]);
      }
  }
}

// ======================= Kernel 2: causal flash attention =======================
// Round 8: K/V staged by per-wave double-buffered LDS DMA (global_load_lds --
// unsinkable, so the depth-1 prefetch is guaranteed in flight across compute),
// gated by s_waitcnt vmcnt(8) (never 0 mid-loop). 512 blocks x 256 thr
// (2 blocks/CU), block = 16-row band pair (j, 255-j) -> uniform 129 kv-32
// tiles per block, waves round-robin (it += 4). LDS K-slot layout is
// chunk-major (lane low bits = kv-row low bits) so frag b128 reads are 2-way
// bank only. O/l combine reuses the wave's own K/V LDS after its loop.
__global__ __launch_bounds__(256, 2) void attn_kernel(
    const short* __restrict__ Qb, const short* __restrict__ Kb,
    const short* __restrict__ Vt, float* __restrict__ out) {
  __shared__ short kvbuf[4][2][4096];  // 64 KB: per wave per buf: [K 32x64 | V 64x32] bf16
  __shared__ float pbuf[4][16 * 36];   // 9.2 KB: per-wave P (16 q x 32 kv fp32, stride 36)
  __shared__ float llds[4][16];

  const int tid  = threadIdx.x;
  const int w    = tid >> 6;
  const int lane = tid & 63;
  const int ln   = lane & 15;
  const int quad = lane >> 4;
  const int g    = blockIdx.x;
  const int b    = g & 3;
  const int j    = g >> 2;  // 0..127

  const short* Kbase = Kb + (size_t)b * S_LEN * DD;
  const short* Vbase = Vt + (size_t)b * DD * S_LEN;
  // per-lane DMA source offsets (shorts)
  const int koff = (lane & 7) * DD + (lane >> 3) * 8;       // K: row lane&7, chunk lane>>3
  const size_t voff = (size_t)(lane & 15) * S_LEN + (lane >> 4) * 8;  // V: row d lane&15, chunk lane>>4
  float* pw = &pbuf[w][0];
  const float4v zz = {0.f, 0.f, 0.f, 0.f};

#define KVSTAGE(KV0, BUF) do {                                                  \
    const short* kp_ = Kbase + (size_t)(KV0) * DD + koff;                       \
    const short* vp_ = Vbase + (KV0) + voff;                                    \
    _Pragma("unroll")                                                           \
    for (int s5 = 0; s5 < 4; ++s5)                                              \
      __builtin_amdgcn_global_load_lds((AS1)(kp_ + s5 * 8 * DD),                \
          (AS3)&kvbuf[w][BUF][s5 * 512], 16, 0, 0);                             \
    _Pragma("unroll")                                                           \
    for (int s5 = 0; s5 < 4; ++s5)                                              \
      __builtin_amdgcn_global_load_lds((AS1)(vp_ + (size_t)(s5 * 16) * S_LEN),  \
          (AS3)&kvbuf[w][BUF][2048 + s5 * 512], 16, 0, 0);                      \
  } while (0)

  for (int ph = 0; ph < 2; ++ph) {
    const int band = ph ? (255 - j) : j;
    const int qb   = band * 16;
    const int qg0  = b * S_LEN + qb;
    const int T    = (qb + 47) >> 5;  // ceil((qb+16)/32) kv-32 tiles

    short8 aQ[2];
#pragma unroll
    for (int h = 0; h < 2; ++h)
      aQ[h] = *(const short8*)(Qb + (size_t)(qg0 + ln) * DD + h * 32 + quad * 8);

    float4v o[4] = {zz, zz, zz, zz};
    float lp[4]  = {0.f, 0.f, 0.f, 0.f};

    if (w < T) KVSTAGE(w * 32, 0);
    int buf = 0;

    for (int it = w; it < T; it += 4) {
      const int kv0 = it * 32;
      if (it + 4 < T) {
        KVSTAGE((it + 4) * 32, buf ^ 1);
        asm volatile("s_waitcnt vmcnt(8)" ::: "memory");  // current buf's 8 DMAs done
      } else {
        asm volatile("s_waitcnt vmcnt(0)" ::: "memory");
      }
      const short* kb_ = &kvbuf[w][buf][0];
      const short* vb_ = &kvbuf[w][buf][2048];

      // S = Q K^T  (K frag: row ct*16+ln -> slot ct*2+(ln>>3), chunk h*4+quad)
      float4v s[2] = {zz, zz};
#pragma unroll
      for (int ct = 0; ct < 2; ++ct)
#pragma unroll
        for (int h = 0; h < 2; ++h) {
          const short8 kf = *(const short8*)(kb_ + (ct * 2 + (ln >> 3)) * 512
                                                 + (ln & 7) * 8 + (h * 4 + quad) * 64);
          s[ct] = MFMA16(aQ[h], kf, s[ct]);
        }

      // V frags: issue ds_reads early (drained by the lgkm wait below)
      short8 vf[4];
#pragma unroll
      for (int dt = 0; dt < 4; ++dt)
        vf[dt] = *(const short8*)(vb_ + dt * 512 + ln * 8 + quad * 128);

      // P = exp2(S) (scores pre-scaled); diagonal mask wave-uniform
      if (kv0 + 31 > qb) {
#pragma unroll
        for (int ct = 0; ct < 2; ++ct)
#pragma unroll
          for (int r = 0; r < 4; ++r) {
            float e = __builtin_amdgcn_exp2f(fminf(s[ct][r], 60.0f));
            if (kv0 + ct * 16 + ln > qb + quad * 4 + r) e = 0.f;
            s[ct][r] = e;
          }
      } else {
#pragma unroll
        for (int ct = 0; ct < 2; ++ct)
#pragma unroll
          for (int r = 0; r < 4; ++r)
            s[ct][r] = __builtin_amdgcn_exp2f(fminf(s[ct][r], 60.0f));
      }
#pragma unroll
      for (int r = 0; r < 4; ++r) lp[r] += s[0][r] + s[1][r];

      // P: C-layout -> row-major LDS fp32 [16][32] (stride 36) -> A-frag
#pragma unroll
      for (int ct = 0; ct < 2; ++ct)
#pragma unroll
        for (int r = 0; r < 4; ++r)
          pw[(quad * 4 + r) * 36 + ct * 16 + ln] = s[ct][r];
      asm volatile("s_waitcnt lgkmcnt(0)" ::: "memory");
      const float4v lo = *(const float4v*)&pw[ln * 36 + quad * 8];
      const float4v hi = *(const float4v*)&pw[ln * 36 + quad * 8 + 4];
      const short8 aP = cvt8(lo, hi);
#pragma unroll
      for (int dt = 0; dt < 4; ++dt)
        o[dt] = MFMA16(aP, vf[dt], o[dt]);

      buf ^= 1;
    }

    // publish partials: l via shfl, O into this wave's OWN kvbuf (done with it)
#pragma unroll
    for (int r = 0; r < 4; ++r) {
      float lr = lp[r];
      lr += __shfl_xor(lr, 1);
      lr += __shfl_xor(lr, 2);
      lr += __shfl_xor(lr, 4);
      lr += __shfl_xor(lr, 8);
      if (ln == 0) llds[w][quad * 4 + r] = lr;
    }
    float* ow = (float*)&kvbuf[w][0][0];
#pragma unroll
    for (int dt = 0; dt < 4; ++dt)
#pragma unroll
      for (int r = 0; r < 4; ++r)
        ow[(quad * 4 + r) * 64 + dt * 16 + ln] = o[dt][r];
    __syncthreads();

    // combine 4 wave partials; coalesced store
#pragma unroll
    for (int jj = 0; jj < 4; ++jj) {
      const int idx = tid + jj * 256;
      const int row = idx >> 6, col = idx & 63;
      float sum = 0.f, lt = 0.f;
#pragma unroll
      for (int wi = 0; wi < 4; ++wi) {
        sum += ((const float*)&kvbuf[wi][0][0])[row * 64 + col];
        lt  += llds[wi][row];
      }
      out[(size_t)(qg0 + row) * DD + col] = sum * __builtin_amdgcn_rcpf(lt);
    }
    __syncthreads();  // kvbuf reused for next phase's DMA
  }
#undef KVSTAGE
}

extern "C" void kernel_launch(void* const* d_in, const int* in_sizes, int n_in,
                              void* d_out, int out_size, void* d_ws, size_t ws_size,
                              hipStream_t stream) {
  const float* x  = (const float*)d_in[0];
  const float* Wq = (const float*)d_in[1];
  const float* Wk = (const float*)d_in[2];
  const float* Wv = (const float*)d_in[3];

  short* Qb  = (short*)d_ws;                       // 2 MB
  short* Kb  = Qb + (size_t)NROWS * DD;            // 2 MB
  short* Vt  = Kb + (size_t)NROWS * DD;            // 2 MB  [b][d][s]
  short* Wb2 = Vt + (size_t)NROWS * DD;            // 384 KB panels

  wcvt_kernel<<<dim3(96), dim3(256), 0, stream>>>(Wq, Wk, Wv, Wb2);
  qkv_kernel<<<dim3(NROWS / 32), dim3(256), 0, stream>>>(x, Wb2, Qb, Kb, Vt);
  attn_kernel<<<dim3(NBATCH * 128), dim3(256), 0, stream>>>(Qb, Kb, Vt, (float*)d_out);
}

// Round 9
// 180.373 us; speedup vs baseline: 1.0062x; 1.0062x over previous
//
#include <hip/hip_runtime.h>
#include <hip/hip_bf16.h>
#include <stdint.h>

typedef __attribute__((ext_vector_type(8))) short  short8;   // 8 bf16 (4 VGPR) MFMA A/B frag
typedef __attribute__((ext_vector_type(4))) short  short4v;
typedef __attribute__((ext_vector_type(4))) float  float4v;  // MFMA C/D frag

#define MFMA16(a, b, c) __builtin_amdgcn_mfma_f32_16x16x32_bf16((a), (b), (c), 0, 0, 0)

#define S_LEN  4096
#define NBATCH 4
#define EMB    1024
#define DD     64
#define NROWS  (NBATCH * S_LEN)  // 16384
#define SCL2   0.1803368801111204f  // (1/sqrt(64)) * log2(e), folded into Wq at wcvt

#define AS1 const __attribute__((address_space(1))) unsigned int*
#define AS3 __attribute__((address_space(3))) unsigned int*

static __device__ __forceinline__ short f2bf(float f) {
  uint32_t u = __float_as_uint(f);
  return (short)((u + 0x7FFFu + ((u >> 16) & 1u)) >> 16);
}
static __device__ __forceinline__ unsigned pk2(float a, float b) {
  union { __hip_bfloat162 h; unsigned u; } z;
  z.h = __float22bfloat162_rn(make_float2(a, b));
  return z.u;
}
static __device__ __forceinline__ short8 cvt8(float4v a, float4v b) {
  union { unsigned u[4]; short8 s; } z;
  z.u[0] = pk2(a[0], a[1]); z.u[1] = pk2(a[2], a[3]);
  z.u[2] = pk2(b[0], b[1]); z.u[3] = pk2(b[2], b[3]);
  return z.s;
}

// ============ Kernel 0: W fp32 -> bf16, reordered into 32-k panels ============
__global__ void wcvt_kernel(const float* __restrict__ Wq, const float* __restrict__ Wk,
                            const float* __restrict__ Wv, short* __restrict__ Wb2) {
  const int t   = blockIdx.x * 256 + threadIdx.x;
  const int row = t >> 7;
  const int k   = (t & 127) * 8;
  const float* src = (row < 64) ? (Wq + (size_t)row * EMB)
                   : (row < 128) ? (Wk + (size_t)(row - 64) * EMB)
                                 : (Wv + (size_t)(row - 128) * EMB);
  const float sc = (row < 64) ? SCL2 : 1.0f;
  float4v a = *(const float4v*)(src + k);
  float4v b = *(const float4v*)(src + k + 4);
#pragma unroll
  for (int i = 0; i < 4; ++i) { a[i] *= sc; b[i] *= sc; }
  *(short8*)(Wb2 + (((k >> 5) * 192 + row) << 5) + (k & 31)) = cvt8(a, b);
}

// ======================= Kernel 1: QKV projection GEMM =======================
// (unchanged from round 6 -- DMA double-buffered, working)
__global__ __launch_bounds__(256, 2) void qkv_kernel(
    const float* __restrict__ x, const short* __restrict__ Wb2,
    short* __restrict__ Qb, short* __restrict__ Kb, short* __restrict__ Vt) {
  __shared__ float As[2][2048];
  __shared__ short Bs[2][12288];

  const int tid  = threadIdx.x;
  const int w    = tid >> 6;
  const int lane = tid & 63;
  const int ln   = lane & 15;
  const int quad = lane >> 4;
  const int m0   = blockIdx.x * 32;
  const int wr   = w & 1;
  const int wc   = w >> 1;

  const int tA0 = 2 * w, tA1 = 2 * w + 1;
  const float* xA0 = x + (size_t)(m0 + ((tA0 >> 2) << 4) + (lane >> 2)) * EMB
                       + ((tA0 & 3) * 4 + (lane & 3)) * 4;
  const float* xA1 = x + (size_t)(m0 + ((tA1 >> 2) << 4) + (lane >> 2)) * EMB
                       + ((tA1 & 3) * 4 + (lane & 3)) * 4;
  const short* wB = Wb2 + (size_t)(6 * w) * 512 + lane * 8;

#define STAGE(S, BUF) do {                                                      \
    __builtin_amdgcn_global_load_lds((AS1)(xA0 + (S) * 64),                     \
        (AS3)&As[BUF][tA0 * 256], 16, 0, 0);                                    \
    __builtin_amdgcn_global_load_lds((AS1)(xA1 + (S) * 64),                     \
        (AS3)&As[BUF][tA1 * 256], 16, 0, 0);                                    \
    _Pragma("unroll")                                                           \
    for (int j = 0; j < 6; ++j)                                                 \
      __builtin_amdgcn_global_load_lds((AS1)(wB + (size_t)(S) * 12288 + j * 512),\
          (AS3)&Bs[BUF][(6 * w + j) * 512], 16, 0, 0);                          \
  } while (0)

  const float4v zz = {0.f, 0.f, 0.f, 0.f};
  float4v acc[6] = {zz, zz, zz, zz, zz, zz};

  STAGE(0, 0);
  int buf = 0;
  for (int s = 0; s < 16; ++s) {
    __syncthreads();
    if (s + 1 < 16) STAGE(s + 1, buf ^ 1);
    short8 aF[2];
#pragma unroll
    for (int h = 0; h < 2; ++h) {
      const int ai = (wr * 4 + 2 * h + (quad >> 1)) * 256 + (ln * 4 + (quad & 1) * 2) * 4;
      const float4v lo = *(const float4v*)&As[buf][ai];
      const float4v hi = *(const float4v*)&As[buf][ai + 4];
      aF[h] = cvt8(lo, hi);
    }
#pragma unroll
    for (int f = 0; f < 6; ++f) {
      const int cf = wc * 6 + f;
      const short8 b0 = *(const short8*)&Bs[buf][(cf * 16 + ln) * 32 + quad * 8];
      const short8 b1 = *(const short8*)&Bs[buf][6144 + (cf * 16 + ln) * 32 + quad * 8];
      if (wc == 0 || f < 2) {
        acc[f] = MFMA16(aF[0], b0, acc[f]);
        acc[f] = MFMA16(aF[1], b1, acc[f]);
      } else {
        acc[f] = MFMA16(b0, aF[0], acc[f]);
        acc[f] = MFMA16(b1, aF[1], acc[f]);
      }
    }
    buf ^= 1;
  }
#undef STAGE

  const int b  = m0 >> 12;
  const int sb = m0 & (S_LEN - 1);
  if (wc == 0) {
#pragma unroll
    for (int f = 0; f < 6; ++f)
#pragma unroll
      for (int r = 0; r < 4; ++r) {
        const int row = m0 + wr * 16 + quad * 4 + r;
        if (f < 4) Qb[(size_t)row * DD + f * 16 + ln] = f2bf(acc[f][r]);
        else       Kb[(size_t)row * DD + (f - 4) * 16 + ln] = f2bf(acc[f][r]);
      }
  } else {
#pragma unroll
    for (int f = 0; f < 2; ++f)
#pragma unroll
      for (int r = 0; r < 4; ++r) {
        const int row = m0 + wr * 16 + quad * 4 + r;
        Kb[(size_t)row * DD + 32 + f * 16 + ln] = f2bf(acc[f][r]);
      }
#pragma unroll
    for (int f = 2; f < 6; ++f)
#pragma unroll
      for (int r = 0; r < 4; ++r) {
        const int d = (f - 2) * 16 + quad * 4 + r;
        Vt[((size_t)b * DD + d) * S_LEN + sb + wr * 16 + ln] = f2bf(acc[f][r]);
      }
  }
}

// ======================= Kernel 2: causal flash attention =======================
// Round 9: same macro structure as round 8 (per-wave DMA dbuf, kv-32 tiles,
// band pair (j,255-j), 512 blocks x 256 thr), but the loop is reordered:
//   vmcnt(0) + ds_read current buf -> regs  FIRST   (DMAs are 1 iter old: free)
//   THEN issue DMA for tile t+1 into the other buf
//   THEN compute (QK, exp, P roundtrip, PV)
// Round 8 issued the DMA before the reads, so the compiler's conservative
// vmcnt wait before the kvbuf ds_reads drained the *new* DMAs every iteration
// (~600 cyc exposed). With reads first, any wait covers only retired loads.
__global__ __launch_bounds__(256, 2) void attn_kernel(
    const short* __restrict__ Qb, const short* __restrict__ Kb,
    const short* __restrict__ Vt, float* __restrict__ out) {
  __shared__ short kvbuf[4][2][4096];  // 64 KB: per wave per buf: [K 32x64 | V 64x32] bf16
  __shared__ float pbuf[4][16 * 36];   // 9.2 KB: per-wave P (16 q x 32 kv fp32, stride 36)
  __shared__ float llds[4][16];

  const int tid  = threadIdx.x;
  const int w    = tid >> 6;
  const int lane = tid & 63;
  const int ln   = lane & 15;
  const int quad = lane >> 4;
  const int g    = blockIdx.x;
  const int b    = g & 3;
  const int j    = g >> 2;  // 0..127

  const short* Kbase = Kb + (size_t)b * S_LEN * DD;
  const short* Vbase = Vt + (size_t)b * DD * S_LEN;
  const int koff = (lane & 7) * DD + (lane >> 3) * 8;
  const size_t voff = (size_t)(lane & 15) * S_LEN + (lane >> 4) * 8;
  float* pw = &pbuf[w][0];
  const float4v zz = {0.f, 0.f, 0.f, 0.f};

#define KVSTAGE(KV0, BUF) do {                                                  \
    const short* kp_ = Kbase + (size_t)(KV0) * DD + koff;                       \
    const short* vp_ = Vbase + (KV0) + voff;                                    \
    _Pragma("unroll")                                                           \
    for (int s5 = 0; s5 < 4; ++s5)                                              \
      __builtin_amdgcn_global_load_lds((AS1)(kp_ + s5 * 8 * DD),                \
          (AS3)&kvbuf[w][BUF][s5 * 512], 16, 0, 0);                             \
    _Pragma("unroll")                                                           \
    for (int s5 = 0; s5 < 4; ++s5)                                              \
      __builtin_amdgcn_global_load_lds((AS1)(vp_ + (size_t)(s5 * 16) * S_LEN),  \
          (AS3)&kvbuf[w][BUF][2048 + s5 * 512], 16, 0, 0);                      \
  } while (0)

  for (int ph = 0; ph < 2; ++ph) {
    const int band = ph ? (255 - j) : j;
    const int qb   = band * 16;
    const int qg0  = b * S_LEN + qb;
    const int T    = (qb + 47) >> 5;  // ceil((qb+16)/32) kv-32 tiles

    short8 aQ[2];
#pragma unroll
    for (int h = 0; h < 2; ++h)
      aQ[h] = *(const short8*)(Qb + (size_t)(qg0 + ln) * DD + h * 32 + quad * 8);

    float4v o[4] = {zz, zz, zz, zz};
    float lp[4]  = {0.f, 0.f, 0.f, 0.f};

    if (w < T) KVSTAGE(w * 32, 0);
    int buf = 0;

    for (int it = w; it < T; it += 4) {
      const int kv0 = it * 32;
      // ---- 1) drain THIS buf's (old) DMAs -- issued a full iteration ago ----
      asm volatile("s_waitcnt vmcnt(0)" ::: "memory");
      const short* kb_ = &kvbuf[w][buf][0];
      const short* vb_ = &kvbuf[w][buf][2048];

      // ---- 2) LDS -> registers, BEFORE issuing any new DMA ----
      short8 kf[2][2];
#pragma unroll
      for (int ct = 0; ct < 2; ++ct)
#pragma unroll
        for (int h = 0; h < 2; ++h)
          kf[ct][h] = *(const short8*)(kb_ + (ct * 2 + (ln >> 3)) * 512
                                           + (ln & 7) * 8 + (h * 4 + quad) * 64);
      short8 vf[4];
#pragma unroll
      for (int dt = 0; dt < 4; ++dt)
        vf[dt] = *(const short8*)(vb_ + dt * 512 + ln * 8 + quad * 128);
      asm volatile("s_waitcnt lgkmcnt(0)" ::: "memory");  // frags in regs

      // ---- 3) now issue next tile's DMA into the other buffer ----
      if (it + 4 < T) KVSTAGE((it + 4) * 32, buf ^ 1);

      // ---- 4) compute ----
      float4v s[2] = {zz, zz};
#pragma unroll
      for (int ct = 0; ct < 2; ++ct)
#pragma unroll
        for (int h = 0; h < 2; ++h)
          s[ct] = MFMA16(aQ[h], kf[ct][h], s[ct]);

      if (kv0 + 31 > qb) {
#pragma unroll
        for (int ct = 0; ct < 2; ++ct)
#pragma unroll
          for (int r = 0; r < 4; ++r) {
            float e = __builtin_amdgcn_exp2f(fminf(s[ct][r], 60.0f));
            if (kv0 + ct * 16 + ln > qb + quad * 4 + r) e = 0.f;
            s[ct][r] = e;
          }
      } else {
#pragma unroll
        for (int ct = 0; ct < 2; ++ct)
#pragma unroll
          for (int r = 0; r < 4; ++r)
            s[ct][r] = __builtin_amdgcn_exp2f(fminf(s[ct][r], 60.0f));
      }
#pragma unroll
      for (int r = 0; r < 4; ++r) lp[r] += s[0][r] + s[1][r];

      // P: C-layout -> row-major LDS fp32 [16][32] (stride 36) -> A-frag
#pragma unroll
      for (int ct = 0; ct < 2; ++ct)
#pragma unroll
        for (int r = 0; r < 4; ++r)
          pw[(quad * 4 + r) * 36 + ct * 16 + ln] = s[ct][r];
      asm volatile("s_waitcnt lgkmcnt(0)" ::: "memory");
      const float4v lo = *(const float4v*)&pw[ln * 36 + quad * 8];
      const float4v hi = *(const float4v*)&pw[ln * 36 + quad * 8 + 4];
      const short8 aP = cvt8(lo, hi);
#pragma unroll
      for (int dt = 0; dt < 4; ++dt)
        o[dt] = MFMA16(aP, vf[dt], o[dt]);

      buf ^= 1;
    }

    // publish partials: l via shfl, O into this wave's OWN kvbuf (done with it)
#pragma unroll
    for (int r = 0; r < 4; ++r) {
      float lr = lp[r];
      lr += __shfl_xor(lr, 1);
      lr += __shfl_xor(lr, 2);
      lr += __shfl_xor(lr, 4);
      lr += __shfl_xor(lr, 8);
      if (ln == 0) llds[w][quad * 4 + r] = lr;
    }
    float* ow = (float*)&kvbuf[w][0][0];
#pragma unroll
    for (int dt = 0; dt < 4; ++dt)
#pragma unroll
      for (int r = 0; r < 4; ++r)
        ow[(quad * 4 + r) * 64 + dt * 16 + ln] = o[dt][r];
    __syncthreads();

    // combine 4 wave partials; coalesced store
#pragma unroll
    for (int jj = 0; jj < 4; ++jj) {
      const int idx = tid + jj * 256;
      const int row = idx >> 6, col = idx & 63;
      float sum = 0.f, lt = 0.f;
#pragma unroll
      for (int wi = 0; wi < 4; ++wi) {
        sum += ((const float*)&kvbuf[wi][0][0])[row * 64 + col];
        lt  += llds[wi][row];
      }
      out[(size_t)(qg0 + row) * DD + col] = sum * __builtin_amdgcn_rcpf(lt);
    }
    __syncthreads();  // kvbuf reused for next phase's DMA
  }
#undef KVSTAGE
}

extern "C" void kernel_launch(void* const* d_in, const int* in_sizes, int n_in,
                              void* d_out, int out_size, void* d_ws, size_t ws_size,
                              hipStream_t stream) {
  const float* x  = (const float*)d_in[0];
  const float* Wq = (const float*)d_in[1];
  const float* Wk = (const float*)d_in[2];
  const float* Wv = (const float*)d_in[3];

  short* Qb  = (short*)d_ws;                       // 2 MB
  short* Kb  = Qb + (size_t)NROWS * DD;            // 2 MB
  short* Vt  = Kb + (size_t)NROWS * DD;            // 2 MB  [b][d][s]
  short* Wb2 = Vt + (size_t)NROWS * DD;            // 384 KB panels

  wcvt_kernel<<<dim3(96), dim3(256), 0, stream>>>(Wq, Wk, Wv, Wb2);
  qkv_kernel<<<dim3(NROWS / 32), dim3(256), 0, stream>>>(x, Wb2, Qb, Kb, Vt);
  attn_kernel<<<dim3(NBATCH * 128), dim3(256), 0, stream>>>(Qb, Kb, Vt, (float*)d_out);
}

// Round 10
// 162.076 us; speedup vs baseline: 1.1198x; 1.1129x over previous
//
#include <hip/hip_runtime.h>
#include <hip/hip_bf16.h>
#include <stdint.h>

typedef __attribute__((ext_vector_type(8))) short  short8;   // 8 bf16 (4 VGPR) MFMA A/B frag
typedef __attribute__((ext_vector_type(4))) short  short4v;
typedef __attribute__((ext_vector_type(4))) float  float4v;  // MFMA C/D frag

#define MFMA16(a, b, c) __builtin_amdgcn_mfma_f32_16x16x32_bf16((a), (b), (c), 0, 0, 0)

#define S_LEN  4096
#define NBATCH 4
#define EMB    1024
#define DD     64
#define NROWS  (NBATCH * S_LEN)  // 16384
#define SCL2   0.1803368801111204f  // (1/sqrt(64)) * log2(e), folded into Wq at wcvt

#define AS1 const __attribute__((address_space(1))) unsigned int*
#define AS3 __attribute__((address_space(3))) unsigned int*

static __device__ __forceinline__ short f2bf(float f) {
  uint32_t u = __float_as_uint(f);
  return (short)((u + 0x7FFFu + ((u >> 16) & 1u)) >> 16);
}
static __device__ __forceinline__ unsigned pk2(float a, float b) {
  union { __hip_bfloat162 h; unsigned u; } z;
  z.h = __float22bfloat162_rn(make_float2(a, b));
  return z.u;
}
static __device__ __forceinline__ short8 cvt8(float4v a, float4v b) {
  union { unsigned u[4]; short8 s; } z;
  z.u[0] = pk2(a[0], a[1]); z.u[1] = pk2(a[2], a[3]);
  z.u[2] = pk2(b[0], b[1]); z.u[3] = pk2(b[2], b[3]);
  return z.s;
}

// ============ Kernel 0: W fp32 -> bf16, reordered into 32-k panels ============
__global__ void wcvt_kernel(const float* __restrict__ Wq, const float* __restrict__ Wk,
                            const float* __restrict__ Wv, short* __restrict__ Wb2) {
  const int t   = blockIdx.x * 256 + threadIdx.x;
  const int row = t >> 7;
  const int k   = (t & 127) * 8;
  const float* src = (row < 64) ? (Wq + (size_t)row * EMB)
                   : (row < 128) ? (Wk + (size_t)(row - 64) * EMB)
                                 : (Wv + (size_t)(row - 128) * EMB);
  const float sc = (row < 64) ? SCL2 : 1.0f;
  float4v a = *(const float4v*)(src + k);
  float4v b = *(const float4v*)(src + k + 4);
#pragma unroll
  for (int i = 0; i < 4; ++i) { a[i] *= sc; b[i] *= sc; }
  *(short8*)(Wb2 + (((k >> 5) * 192 + row) << 5) + (k & 31)) = cvt8(a, b);
}

// ======================= Kernel 1: QKV projection GEMM =======================
// (unchanged from round 6 -- DMA double-buffered, working)
__global__ __launch_bounds__(256, 2) void qkv_kernel(
    const float* __restrict__ x, const short* __restrict__ Wb2,
    short* __restrict__ Qb, short* __restrict__ Kb, short* __restrict__ Vt) {
  __shared__ float As[2][2048];
  __shared__ short Bs[2][12288];

  const int tid  = threadIdx.x;
  const int w    = tid >> 6;
  const int lane = tid & 63;
  const int ln   = lane & 15;
  const int quad = lane >> 4;
  const int m0   = blockIdx.x * 32;
  const int wr   = w & 1;
  const int wc   = w >> 1;

  const int tA0 = 2 * w, tA1 = 2 * w + 1;
  const float* xA0 = x + (size_t)(m0 + ((tA0 >> 2) << 4) + (lane >> 2)) * EMB
                       + ((tA0 & 3) * 4 + (lane & 3)) * 4;
  const float* xA1 = x + (size_t)(m0 + ((tA1 >> 2) << 4) + (lane >> 2)) * EMB
                       + ((tA1 & 3) * 4 + (lane & 3)) * 4;
  const short* wB = Wb2 + (size_t)(6 * w) * 512 + lane * 8;

#define STAGE(S, BUF) do {                                                      \
    __builtin_amdgcn_global_load_lds((AS1)(xA0 + (S) * 64),                     \
        (AS3)&As[BUF][tA0 * 256], 16, 0, 0);                                    \
    __builtin_amdgcn_global_load_lds((AS1)(xA1 + (S) * 64),                     \
        (AS3)&As[BUF][tA1 * 256], 16, 0, 0);                                    \
    _Pragma("unroll")                                                           \
    for (int j = 0; j < 6; ++j)                                                 \
      __builtin_amdgcn_global_load_lds((AS1)(wB + (size_t)(S) * 12288 + j * 512),\
          (AS3)&Bs[BUF][(6 * w + j) * 512], 16, 0, 0);                          \
  } while (0)

  const float4v zz = {0.f, 0.f, 0.f, 0.f};
  float4v acc[6] = {zz, zz, zz, zz, zz, zz};

  STAGE(0, 0);
  int buf = 0;
  for (int s = 0; s < 16; ++s) {
    __syncthreads();
    if (s + 1 < 16) STAGE(s + 1, buf ^ 1);
    short8 aF[2];
#pragma unroll
    for (int h = 0; h < 2; ++h) {
      const int ai = (wr * 4 + 2 * h + (quad >> 1)) * 256 + (ln * 4 + (quad & 1) * 2) * 4;
      const float4v lo = *(const float4v*)&As[buf][ai];
      const float4v hi = *(const float4v*)&As[buf][ai + 4];
      aF[h] = cvt8(lo, hi);
    }
#pragma unroll
    for (int f = 0; f < 6; ++f) {
      const int cf = wc * 6 + f;
      const short8 b0 = *(const short8*)&Bs[buf][(cf * 16 + ln) * 32 + quad * 8];
      const short8 b1 = *(const short8*)&Bs[buf][6144 + (cf * 16 + ln) * 32 + quad * 8];
      if (wc == 0 || f < 2) {
        acc[f] = MFMA16(aF[0], b0, acc[f]);
        acc[f] = MFMA16(aF[1], b1, acc[f]);
      } else {
        acc[f] = MFMA16(b0, aF[0], acc[f]);
        acc[f] = MFMA16(b1, aF[1], acc[f]);
      }
    }
    buf ^= 1;
  }
#undef STAGE

  const int b  = m0 >> 12;
  const int sb = m0 & (S_LEN - 1);
  if (wc == 0) {
#pragma unroll
    for (int f = 0; f < 6; ++f)
#pragma unroll
      for (int r = 0; r < 4; ++r) {
        const int row = m0 + wr * 16 + quad * 4 + r;
        if (f < 4) Qb[(size_t)row * DD + f * 16 + ln] = f2bf(acc[f][r]);
        else       Kb[(size_t)row * DD + (f - 4) * 16 + ln] = f2bf(acc[f][r]);
      }
  } else {
#pragma unroll
    for (int f = 0; f < 2; ++f)
#pragma unroll
      for (int r = 0; r < 4; ++r) {
        const int row = m0 + wr * 16 + quad * 4 + r;
        Kb[(size_t)row * DD + 32 + f * 16 + ln] = f2bf(acc[f][r]);
      }
#pragma unroll
    for (int f = 2; f < 6; ++f)
#pragma unroll
      for (int r = 0; r < 4; ++r) {
        const int d = (f - 2) * 16 + quad * 4 + r;
        Vt[((size_t)b * DD + d) * S_LEN + sb + wr * 16 + ln] = f2bf(acc[f][r]);
      }
  }
}

// ======================= Kernel 2: causal flash attention =======================
// Round 10: FAT per-wave tiles (32 q x 32 kv -- r7's amortization) + per-wave
// TRIPLE-buffered LDS DMA staging, depth-2 prefetch, vmcnt(8) steady-state.
// 256 blocks x 256 thr (1/CU), block = 32-row band pair (j, 127-j), two
// sequential phases; waves take kv-32 tiles round-robin. DMA lane maps are
// contiguous-with-XOR-swizzle so transactions coalesce AND frag b128 reads
// are bank-uniform. Order per iter: wait(old) -> ds_read -> issue DMA(t+2)
// -> compute (so any compiler-inserted wait covers only old loads).
#define PSTRW 34  // P row stride in f32 words: 2-way write banks (free)

__global__ __launch_bounds__(256, 1) void attn_kernel(
    const short* __restrict__ Qb, const short* __restrict__ Kb,
    const short* __restrict__ Vt, float* __restrict__ out) {
  __shared__ short kvbuf[4][3][4096];   // 96 KB: per wave x 3 bufs x (K 4KB | V 4KB)
  __shared__ float pbuf[4][32 * PSTRW]; // 17.4 KB per-wave P
  __shared__ float llds[4][32];

  const int tid  = threadIdx.x;
  const int w    = tid >> 6;
  const int lane = tid & 63;
  const int ln   = lane & 15;
  const int quad = lane >> 4;
  const int g    = blockIdx.x;
  const int b    = g & 3;   // batch == XCD (g%8 dispatch => per-XCD batch locality)
  const int j    = g >> 2;  // 0..63

  const short* Kbase = Kb + (size_t)b * S_LEN * DD;
  const short* Vbase = Vt + (size_t)b * DD * S_LEN;
  // DMA lane maps (shorts). K: lane i -> kv-row i>>3, d-chunk (i&7)^(i>>3)
  // (contiguous 1KB per instr, XOR-swizzled so frag reads are conflict-free).
  // V: lane i -> d-row i>>2, kv-chunk (i&3)^((i>>2)&3) (16 x 64B segs/instr).
  const int    klane = (lane >> 3) * DD + (((lane & 7) ^ (lane >> 3))) * 8;
  const size_t vlane = (size_t)(lane >> 2) * S_LEN + (((lane & 3) ^ ((lane >> 2) & 3))) * 8;
  float* pw = &pbuf[w][0];
  const float4v zz = {0.f, 0.f, 0.f, 0.f};

#define KVSTAGE(KV0, BUF) do {                                                  \
    const short* kp_ = Kbase + (size_t)(KV0) * DD + klane;                      \
    const short* vp_ = Vbase + (KV0) + vlane;                                   \
    _Pragma("unroll")                                                           \
    for (int s5 = 0; s5 < 4; ++s5)                                              \
      __builtin_amdgcn_global_load_lds((AS1)(kp_ + s5 * 8 * DD),                \
          (AS3)&kvbuf[w][BUF][s5 * 512], 16, 0, 0);                             \
    _Pragma("unroll")                                                           \
    for (int s5 = 0; s5 < 4; ++s5)                                              \
      __builtin_amdgcn_global_load_lds((AS1)(vp_ + (size_t)(s5 * 16) * S_LEN),  \
          (AS3)&kvbuf[w][BUF][2048 + s5 * 512], 16, 0, 0);                      \
  } while (0)

  for (int ph = 0; ph < 2; ++ph) {
    const int band = ph ? (127 - j) : j;
    const int qb   = band * 32;
    const int qg0  = b * S_LEN + qb;
    const int T    = band + 1;  // kv-32 tiles: ceil((qb+32)/32)

    short8 aQ[2][2];
#pragma unroll
    for (int rfi = 0; rfi < 2; ++rfi)
#pragma unroll
      for (int h = 0; h < 2; ++h)
        aQ[rfi][h] = *(const short8*)(Qb + (size_t)(qg0 + rfi * 16 + ln) * DD + h * 32 + quad * 8);

    float4v o[2][4];
    float lp[2][4];
#pragma unroll
    for (int rfi = 0; rfi < 2; ++rfi)
#pragma unroll
      for (int d = 0; d < 4; ++d) { o[rfi][d] = zz; lp[rfi][d] = 0.f; }

    // prologue: stage tiles w and w+4 (bufs 0,1)
    if (w < T)     KVSTAGE(w * 32, 0);
    if (w + 4 < T) KVSTAGE((w + 4) * 32, 1);
    int nbuf = 0;

    for (int it = w; it < T; it += 4) {
      const int kv0 = it * 32;
      // 1) wait for tile `it` (issued >= 2 iters ago); keep newer in flight
      if (it + 4 < T) { asm volatile("s_waitcnt vmcnt(8)" ::: "memory"); }
      else            { asm volatile("s_waitcnt vmcnt(0)" ::: "memory"); }
      const short* kb_ = &kvbuf[w][nbuf][0];
      const short* vb_ = &kvbuf[w][nbuf][2048];

      // 2) LDS -> registers (swizzled addressing matches DMA layout)
      short8 kf[2][2];
#pragma unroll
      for (int ct = 0; ct < 2; ++ct)
#pragma unroll
        for (int h = 0; h < 2; ++h)
          kf[ct][h] = *(const short8*)(kb_ + (2 * ct + (ln >> 3)) * 512
                                           + (ln & 7) * 64 + (((h * 4 + quad) ^ (ln & 7))) * 8);
      short8 vf[4];
#pragma unroll
      for (int dt = 0; dt < 4; ++dt)
        vf[dt] = *(const short8*)(vb_ + dt * 512 + ln * 32 + ((quad ^ (ln & 3))) * 8);
      asm volatile("s_waitcnt lgkmcnt(0)" ::: "memory");

      // 3) issue DMA for tile it+8 (depth-2)
      if (it + 8 < T) KVSTAGE((it + 8) * 32, (nbuf + 2 >= 3) ? (nbuf - 1) : (nbuf + 2));

      // 4) compute: S = Q K^T
      float4v s[2][2];
#pragma unroll
      for (int rfi = 0; rfi < 2; ++rfi)
#pragma unroll
        for (int ct = 0; ct < 2; ++ct) {
          s[rfi][ct] = MFMA16(aQ[rfi][0], kf[ct][0], zz);
          s[rfi][ct] = MFMA16(aQ[rfi][1], kf[ct][1], s[rfi][ct]);
        }

      // P = exp2(S); exactly one masked (diagonal) tile per band
      if (it == band) {
#pragma unroll
        for (int rfi = 0; rfi < 2; ++rfi)
#pragma unroll
          for (int ct = 0; ct < 2; ++ct)
#pragma unroll
            for (int r = 0; r < 4; ++r) {
              float e = __builtin_amdgcn_exp2f(fminf(s[rfi][ct][r], 60.0f));
              if (kv0 + ct * 16 + ln > qb + rfi * 16 + quad * 4 + r) e = 0.f;
              s[rfi][ct][r] = e;
            }
      } else {
#pragma unroll
        for (int rfi = 0; rfi < 2; ++rfi)
#pragma unroll
          for (int ct = 0; ct < 2; ++ct)
#pragma unroll
            for (int r = 0; r < 4; ++r)
              s[rfi][ct][r] = __builtin_amdgcn_exp2f(fminf(s[rfi][ct][r], 60.0f));
      }
#pragma unroll
      for (int rfi = 0; rfi < 2; ++rfi)
#pragma unroll
        for (int r = 0; r < 4; ++r)
          lp[rfi][r] += s[rfi][0][r] + s[rfi][1][r];

      // P: C-layout -> row-major LDS fp32 [32][PSTRW] -> A-frags
#pragma unroll
      for (int rfi = 0; rfi < 2; ++rfi)
#pragma unroll
        for (int ct = 0; ct < 2; ++ct)
#pragma unroll
          for (int r = 0; r < 4; ++r)
            pw[(rfi * 16 + quad * 4 + r) * PSTRW + ct * 16 + ln] = s[rfi][ct][r];
      asm volatile("s_waitcnt lgkmcnt(0)" ::: "memory");
      short8 aP[2];
#pragma unroll
      for (int rfi = 0; rfi < 2; ++rfi) {
        const float4v lo = *(const float4v*)&pw[(rfi * 16 + ln) * PSTRW + quad * 8];
        const float4v hi = *(const float4v*)&pw[(rfi * 16 + ln) * PSTRW + quad * 8 + 4];
        aP[rfi] = cvt8(lo, hi);
      }
#pragma unroll
      for (int rfi = 0; rfi < 2; ++rfi)
#pragma unroll
        for (int dt = 0; dt < 4; ++dt)
          o[rfi][dt] = MFMA16(aP[rfi], vf[dt], o[rfi][dt]);

      nbuf = (nbuf + 1 >= 3) ? 0 : nbuf + 1;
    }

    // publish partials: l via shfl; O into this wave's OWN kvbuf region
#pragma unroll
    for (int rfi = 0; rfi < 2; ++rfi)
#pragma unroll
      for (int r = 0; r < 4; ++r) {
        float lr = lp[rfi][r];
        lr += __shfl_xor(lr, 1);
        lr += __shfl_xor(lr, 2);
        lr += __shfl_xor(lr, 4);
        lr += __shfl_xor(lr, 8);
        if (ln == 0) llds[w][rfi * 16 + quad * 4 + r] = lr;
      }
    float* ow = (float*)&kvbuf[w][0][0];  // 8 KB needed, wave-private, DMAs drained
#pragma unroll
    for (int rfi = 0; rfi < 2; ++rfi)
#pragma unroll
      for (int dt = 0; dt < 4; ++dt)
#pragma unroll
        for (int r = 0; r < 4; ++r)
          ow[(rfi * 16 + quad * 4 + r) * 64 + dt * 16 + ln] = o[rfi][dt][r];
    __syncthreads();

    // combine 4 wave partials; coalesced store (32 rows x 64 cols)
#pragma unroll
    for (int jj = 0; jj < 8; ++jj) {
      const int idx = tid + jj * 256;
      const int row = idx >> 6, col = idx & 63;
      float sum = 0.f, lt = 0.f;
#pragma unroll
      for (int wi = 0; wi < 4; ++wi) {
        sum += ((const float*)&kvbuf[wi][0][0])[row * 64 + col];
        lt  += llds[wi][row];
      }
      out[(size_t)(qg0 + row) * DD + col] = sum * __builtin_amdgcn_rcpf(lt);
    }
    __syncthreads();  // kvbuf reused for next phase's DMA
  }
#undef KVSTAGE
}

extern "C" void kernel_launch(void* const* d_in, const int* in_sizes, int n_in,
                              void* d_out, int out_size, void* d_ws, size_t ws_size,
                              hipStream_t stream) {
  const float* x  = (const float*)d_in[0];
  const float* Wq = (const float*)d_in[1];
  const float* Wk = (const float*)d_in[2];
  const float* Wv = (const float*)d_in[3];

  short* Qb  = (short*)d_ws;                       // 2 MB
  short* Kb  = Qb + (size_t)NROWS * DD;            // 2 MB
  short* Vt  = Kb + (size_t)NROWS * DD;            // 2 MB  [b][d][s]
  short* Wb2 = Vt + (size_t)NROWS * DD;            // 384 KB panels

  wcvt_kernel<<<dim3(96), dim3(256), 0, stream>>>(Wq, Wk, Wv, Wb2);
  qkv_kernel<<<dim3(NROWS / 32), dim3(256), 0, stream>>>(x, Wb2, Qb, Kb, Vt);
  attn_kernel<<<dim3(NBATCH * 64), dim3(256), 0, stream>>>(Qb, Kb, Vt, (float*)d_out);
}